// Round 10
// baseline (253.460 us; speedup 1.0000x reference)
//
#include <hip/hip_runtime.h>
#include <hip/hip_bf16.h>
#include <stdint.h>

#define NB 4
#define NS 2048
#define ND 1024
#define NH 16
#define NHS 64
#define NEG_BIG (-1e30f)
// 1/sqrt(HS) * log2(e): folds softmax exp->exp2 into Q scaling (exactly softmax-invariant)
#define Q_SCALE 0.18033688011112042f

typedef __bf16 bf16x8 __attribute__((ext_vector_type(8)));
typedef float floatx4 __attribute__((ext_vector_type(4)));
typedef short s16x4 __attribute__((ext_vector_type(4)));

#if defined(__has_builtin)
#if __has_builtin(__builtin_amdgcn_mfma_f32_16x16x16bf16_1k)
#define HAVE_MFMA1K 1
#endif
#endif
#ifndef HAVE_MFMA1K
#define HAVE_MFMA1K 0
#endif

static constexpr size_t WSLAB = (size_t)NH * ND * NHS;        // 2^20 elems per weight mat
static constexpr size_t QSLAB = (size_t)NB * NH * NS * NHS;   // 8M elems per QKV/Y slab
static constexpr size_t XSLAB = (size_t)NB * NS * ND;         // 8M elems (x as bf16)

__device__ __forceinline__ uint16_t f2b(float f) {
    union { __hip_bfloat16 h; uint16_t u; } cv;
    cv.h = __float2bfloat16(f);
    return cv.u;
}

// async global->LDS, 16B per lane. LDS dest = wave-uniform base + lane*16 (UNPADDED only).
__device__ __forceinline__ void gll16(const void* g, void* l) {
  __builtin_amdgcn_global_load_lds(
      (__attribute__((address_space(1))) void*)(uintptr_t)g,
      (__attribute__((address_space(3))) void*)(uintptr_t)l,
      16, 0, 0);
}

// ---------------- kernel P: merged x-convert + weight convert/transpose ----------------
__global__ __launch_bounds__(256) void k_prep(
    const float* __restrict__ x, const float* __restrict__ Wq,
    const float* __restrict__ Wk, const float* __restrict__ Wv,
    const float* __restrict__ Wo, uint16_t* __restrict__ xb,
    uint16_t* __restrict__ wt) {
  __shared__ __align__(16) uint16_t T[64][72];
  int bid = blockIdx.x;
  int tid = threadIdx.x;
  if (bid < 4096) {
    size_t i0 = ((size_t)bid * 256 + tid) * 8;
    float4 f0 = *(const float4*)&x[i0];
    float4 f1 = *(const float4*)&x[i0 + 4];
    __align__(16) uint16_t tmp[8];
    tmp[0] = f2b(f0.x); tmp[1] = f2b(f0.y); tmp[2] = f2b(f0.z); tmp[3] = f2b(f0.w);
    tmp[4] = f2b(f1.x); tmp[5] = f2b(f1.y); tmp[6] = f2b(f1.z); tmp[7] = f2b(f1.w);
    *(uint4*)&xb[i0] = *(uint4*)tmp;
    return;
  }
  bid -= 4096;
  const float* src; uint16_t* dst;
  int srcStride, dstStride, r0, c0;
  if (bid < 768) {
    int mat = bid >> 8;
    int rem = bid & 255;
    int h = rem >> 4, dt = rem & 15;
    const float* W = (mat == 0) ? Wq : (mat == 1) ? Wk : Wv;
    src = W + (size_t)h * (ND * NHS);
    dst = wt + (size_t)mat * WSLAB + (size_t)h * (NHS * ND);
    srcStride = NHS; dstStride = ND;
    r0 = dt * 64; c0 = 0;
  } else {
    int rem = bid - 768;
    int dt = rem >> 4, et = rem & 15;
    src = Wo; dst = wt + 3 * WSLAB;
    srcStride = ND; dstStride = ND;
    r0 = dt * 64; c0 = et * 64;
  }
  for (int u = tid; u < 1024; u += 256) {
    int row = u >> 4, cq = u & 15;
    float4 f = *(const float4*)&src[(size_t)(r0 + row) * srcStride + c0 + cq * 4];
    uint16_t* p = &T[row][cq * 4];
    p[0] = f2b(f.x); p[1] = f2b(f.y); p[2] = f2b(f.z); p[3] = f2b(f.w);
  }
  __syncthreads();
  for (int u = tid; u < 512; u += 256) {
    int c = u >> 3, cg = u & 7;
    __align__(16) uint16_t tmp[8];
    for (int j = 0; j < 8; j++) tmp[j] = T[cg * 8 + j][c];
    *(uint4*)&dst[(size_t)(c0 + c) * dstStride + r0 + cg * 8] = *(uint4*)tmp;
  }
}

// ---------------- kernel 1: fused QKV GEMM, 256x128 multi-phase counted-vmcnt (T3+T4) ----
// Round-9: 4th config at the 2-phase ~700TF plateau -> port the m201 schedule faithfully.
// Geometry: BM=256, BN=128, BK=64; 512 thr = 8 waves (2M x 4N); per-wave C = 128x32 ->
// acc[8][2] = 64 VGPR (budget ~125 at (512,2) -- no spill, r3/r7 check).
// Grid 32m x 24n = 768 = EXACTLY 3 rounds at 1 block/CU (144KB LDS) -> plateau-rate
// failure mode is break-even vs round-9's 70.7us.
// LDS: 3-deep ring x {A: 2 K-half units of 256rx32K (16KB, 2 gll16/thr); B: 2 units of
// 128rx32K (8KB, 1 gll16/thr)} = 144KB. Units use the r4-PROVEN both-sides swizzle
// (source chunk ^= (row>>2)&3; reads ^= l16>>2) -> bank floor.
// Schedule: 2 phases/K-step (kk=lo/hi). Phase = {10 ds_read_b128 (8 A-frags + 2 B);
// issue 3 gll16 for step t+2; vmcnt(9); ONE barrier; setprio(1); 16 MFMA; setprio(0)}.
// Loads stay in flight across 4 phase barriers (T4: never drain to 0 mid-loop).
// Ledger: stage at ph(t) targets slot (t+2)%3 whose occupant was read at ph(t-1), >=1
// barrier earlier (reads lgkm-drained before that wave's MFMA, which precedes its
// barrier arrival). vmcnt(9) = 3 stage-groups in flight; tail t=14: 6,3; t=15: 0.
__global__ __launch_bounds__(512, 2) void k_qkv(
    const uint16_t* __restrict__ xb, const uint16_t* __restrict__ wt,
    uint16_t* __restrict__ qk, uint16_t* __restrict__ vt) {
  __shared__ __align__(16) uint16_t L[73728];   // 147456 B: A [0,49152), B [49152,73728)

  int bid = blockIdx.x;
  int xcd = bid & 7, idx = bid >> 3;     // 96 tiles per XCD chunk
  int mtile = xcd * 4 + (idx & 3);       // 4 m-tiles per XCD, inner (2MB A L2-resident)
  int ntile = idx >> 2;                  // 24 n-tiles, outer
  int m0 = mtile * 256;
  int n0 = ntile * 128;

  int tid = threadIdx.x;
  int wave = tid >> 6, lane = tid & 63, quad = lane >> 4, l16 = lane & 15;
  int wr = wave >> 2, wc = wave & 3;

  // staging: thread covers (row = tid>>2, chunk = tid&3) of a 128-row x 32-K unit;
  // source chunk pre-swizzled with key (row>>2)&3 = (tid>>4)&3 (rule 21 both-sides).
  int swc = ((tid & 3) ^ ((tid >> 4) & 3)) * 8;
  const uint16_t* pA = xb + (size_t)(m0 + (tid >> 2)) * ND + swc;
  const uint16_t* pB = wt + (size_t)(n0 + (tid >> 2)) * ND + swc;
  const int stOff = tid * 8;             // gll16 dest: wave-uniform + lane*16B

  // frag-read bases; chunk XOR'd with the same key (l16>>2)
  const int rq = (quad ^ (l16 >> 2)) * 8;
  const int offA = wr * 4096 + l16 * 32 + rq;    // + mt*512, + slot base
  const int offB = l16 * 32 + rq;                // + (wc*32+nt*16)*32 folded below

  floatx4 acc[8][2];
  #pragma unroll
  for (int i = 0; i < 8; i++)
    #pragma unroll
    for (int j = 0; j < 2; j++) acc[i][j] = (floatx4){0.f, 0.f, 0.f, 0.f};

  // A unit (T,KK) -> slot (P*2+KK)*8192 (2 gll16: rows 0-127, 128-255)
#define SA(T, KK, P)                                                            \
  do {                                                                          \
    if ((T) < 16) {                                                             \
      int kb_ = (T) * 64 + (KK) * 32;                                           \
      gll16(pA + kb_, &L[((P) * 2 + (KK)) * 8192 + stOff]);                     \
      gll16(pA + 128 * ND + kb_, &L[((P) * 2 + (KK)) * 8192 + 4096 + stOff]);   \
    }                                                                           \
  } while (0)
  // B unit (T,KK) -> slot 49152 + (P*2+KK)*4096 (1 gll16)
#define SB(T, KK, P)                                                            \
  do {                                                                          \
    if ((T) < 16) {                                                             \
      int kb_ = (T) * 64 + (KK) * 32;                                           \
      gll16(pB + kb_, &L[49152 + ((P) * 2 + (KK)) * 4096 + stOff]);             \
    }                                                                           \
  } while (0)

#define PH_BAR()                         \
  do {                                   \
    asm volatile("" ::: "memory");       \
    __builtin_amdgcn_s_barrier();        \
    asm volatile("" ::: "memory");       \
  } while (0)

  // prologue: steady-state issue order {lo(0), hi(0), lo(1), hi(1)} = 4 groups of 3
  SA(0, 0, 0); SB(0, 0, 0);
  SA(0, 1, 0); SB(0, 1, 0);
  SA(1, 0, 1); SB(1, 0, 1);
  SA(1, 1, 1); SB(1, 1, 1);
  asm volatile("s_waitcnt vmcnt(9)" ::: "memory");   // drain lo(0); 3 groups in flight
  PH_BAR();

#define MFMA16()                                                                          \
  _Pragma("unroll")                                                                       \
  for (int mt_ = 0; mt_ < 8; mt_++)                                                       \
    _Pragma("unroll")                                                                     \
    for (int nt_ = 0; nt_ < 2; nt_++)                                                     \
      acc[mt_][nt_] = __builtin_amdgcn_mfma_f32_16x16x32_bf16(af[mt_], bfr[nt_], acc[mt_][nt_], 0, 0, 0)

  int p = 0, p2 = 2;   // t%3, (t+2)%3
  for (int t = 0; t < 16; ++t) {
    {
      // ---- ph0 (kk=0): read lo(t); stage lo(t+2); vmcnt guards ph1's hi(t) ----
      int aB = (p * 2 + 0) * 8192;
      int bB = 49152 + (p * 2 + 0) * 4096 + (wc * 32) * 32;
      bf16x8 af[8], bfr[2];
      #pragma unroll
      for (int i = 0; i < 8; i++) af[i] = *(const bf16x8*)&L[aB + offA + i * 512];
      #pragma unroll
      for (int i = 0; i < 2; i++) bfr[i] = *(const bf16x8*)&L[bB + offB + i * 512];
      SA(t + 2, 0, p2); SB(t + 2, 0, p2);
      if (t <= 13)      { asm volatile("s_waitcnt vmcnt(9)" ::: "memory"); }
      else if (t == 14) { asm volatile("s_waitcnt vmcnt(6)" ::: "memory"); }
      else              { asm volatile("s_waitcnt vmcnt(0)" ::: "memory"); }
      PH_BAR();
      __builtin_amdgcn_s_setprio(1);
      MFMA16();
      __builtin_amdgcn_s_setprio(0);
    }
    {
      // ---- ph1 (kk=1): read hi(t); stage hi(t+2); vmcnt guards ph0(t+1)'s lo(t+1) ----
      int aB = (p * 2 + 1) * 8192;
      int bB = 49152 + (p * 2 + 1) * 4096 + (wc * 32) * 32;
      bf16x8 af[8], bfr[2];
      #pragma unroll
      for (int i = 0; i < 8; i++) af[i] = *(const bf16x8*)&L[aB + offA + i * 512];
      #pragma unroll
      for (int i = 0; i < 2; i++) bfr[i] = *(const bf16x8*)&L[bB + offB + i * 512];
      SA(t + 2, 1, p2); SB(t + 2, 1, p2);
      if (t <= 13)      { asm volatile("s_waitcnt vmcnt(9)" ::: "memory"); PH_BAR(); }
      else if (t == 14) { asm volatile("s_waitcnt vmcnt(3)" ::: "memory"); PH_BAR(); }
      // t == 15: last phase, no further reads -> no wait/barrier
      __builtin_amdgcn_s_setprio(1);
      MFMA16();
      __builtin_amdgcn_s_setprio(0);
    }
    p = (p == 2) ? 0 : p + 1;
    p2 = (p2 == 2) ? 0 : p2 + 1;
  }
#undef MFMA16
#undef SA
#undef SB
#undef PH_BAR

  // n-decomposition: head hh, element e within head (per-wave n-range = wc*32, as r4)
  int matid = n0 >> 10;
  int b = m0 >> 11;
  if (matid == 2) {
    // ---- V blocks: store V^T ([b,h,e,s]) directly from registers (uint2, s-contiguous) ----
    int hh = ((n0 - 2048) >> 6) + (wc >> 1);
    #pragma unroll
    for (int nt = 0; nt < 2; nt++) {
      int e = (wc & 1) * 32 + nt * 16 + l16;
      uint16_t* vrow = vt + ((size_t)(b * 16 + hh) * 64 + e) * NS;
      #pragma unroll
      for (int mt = 0; mt < 8; mt++) {
        __align__(8) uint16_t t4v[4];
        #pragma unroll
        for (int r = 0; r < 4; r++) t4v[r] = f2b(acc[mt][nt][r]);
        int s = (m0 & 2047) + wr * 128 + mt * 16 + quad * 4;
        *(uint2*)&vrow[s] = *(uint2*)t4v;
      }
    }
  } else {
    // ---- Q/K blocks: scatter to [b,h,s,e] with Q pre-scale ----
    float scale = (matid == 0) ? Q_SCALE : 1.0f;
    uint16_t* base = qk + (size_t)matid * QSLAB;
    int hh = ((n0 & 1023) >> 6) + (wc >> 1);
    #pragma unroll
    for (int mt = 0; mt < 8; mt++) {
      int s = (m0 & 2047) + wr * 128 + mt * 16 + quad * 4;
      size_t rbase = ((size_t)(b * 16 + hh) * NS + s) * NHS;
      #pragma unroll
      for (int nt = 0; nt < 2; nt++)
        #pragma unroll
        for (int r = 0; r < 4; r++)
          base[rbase + (size_t)r * NHS + (wc & 1) * 32 + nt * 16 + l16] =
              f2b(acc[mt][nt][r] * scale);
    }
  }
}

#if HAVE_MFMA1K
// ---------------- kernel 2: causal attention, S^T trick, gll16 staging, 1 barrier/step --
// (round-9 verified: dropped out of top-5; keep)
__global__ __launch_bounds__(256, 4) void k_attn(
    const uint16_t* __restrict__ Q, const uint16_t* __restrict__ K,
    const uint16_t* __restrict__ VT, uint16_t* __restrict__ Y) {
  __shared__ __align__(16) uint16_t Ks[2][4096];   // [buf][k*64 + swz e-chunk]
  __shared__ __align__(16) uint16_t Vs[2][4096];   // [buf][e*64 + swz key-chunk]
  int bh = blockIdx.y;
  int b = bh >> 4, h = bh & 15;
  int ta = blockIdx.x;       // 0..15
  int tb = 31 - ta;          // 16..31
  const uint16_t* Qp = Q + (size_t)bh * (NS * NHS);
  const uint16_t* Kp = K + (size_t)bh * (NS * NHS);
  const uint16_t* Vp = VT + (size_t)bh * (NS * NHS);  // [e][key]
  int tid = threadIdx.x;
  int wv = tid >> 6, lane = tid & 63, quad = lane >> 4, l16 = lane & 15;

  // gll16 staging map: wave wv covers rows [wv*16, wv*16+16) in two 8-row groups.
  int srow = lane >> 3;                       // row offset in 8-row group (= row&7)
  int swOff = ((lane & 7) ^ srow) * 8;        // pre-swizzled source chunk (u16)
  int stRow0 = wv * 16 + srow;
  int stRow1 = wv * 16 + 8 + srow;
  const int dst0 = wv * 1024;                 // wave-uniform LDS dest (u16)
  const int dst1 = wv * 1024 + 512;

#define STAGE_KV(KT, BUF)                                                         \
  do {                                                                            \
    int kt_ = (KT);                                                               \
    gll16(Kp + (size_t)(kt_ * 64 + stRow0) * NHS + swOff, &Ks[BUF][dst0]);        \
    gll16(Kp + (size_t)(kt_ * 64 + stRow1) * NHS + swOff, &Ks[BUF][dst1]);        \
    gll16(Vp + (size_t)stRow0 * NS + kt_ * 64 + swOff, &Vs[BUF][dst0]);           \
    gll16(Vp + (size_t)stRow1 * NS + kt_ * 64 + swOff, &Vs[BUF][dst1]);           \
  } while (0)

  // swizzled frag-read column offsets (u16 within a 64-u16 row)
  int e3 = l16 & 7;
  int kc0 = (quad ^ e3) * 8;              // kb0: logical chunk quad
  int kc1 = ((4 | quad) ^ e3) * 8;        // kb1: logical chunk 4+quad
  int vql = (quad & 1) * 4;
  int vqh = quad >> 1;
  int vcol[4];
  #pragma unroll
  for (int ct = 0; ct < 4; ct++)
    vcol[ct] = (((ct * 2 + vqh) ^ e3) * 8) + vql;

  // Q fragments from global; B operand of S^T = K.Q^T (n = q-row = l16)
  int rA = ta * 64 + wv * 16 + l16;
  int rB = tb * 64 + wv * 16 + l16;
  bf16x8 aqA0 = *(const bf16x8*)&Qp[(size_t)rA * NHS + quad * 8];
  bf16x8 aqA1 = *(const bf16x8*)&Qp[(size_t)rA * NHS + 32 + quad * 8];
  bf16x8 aqB0 = *(const bf16x8*)&Qp[(size_t)rB * NHS + quad * 8];
  bf16x8 aqB1 = *(const bf16x8*)&Qp[(size_t)rB * NHS + 32 + quad * 8];

  float lAs = 0.f, lBs = 0.f;          // per-lane row-sum (all p of a lane share q-row l16)
  floatx4 oA[4], oB[4];                // O^T accumulators, one per e-tile
  for (int et = 0; et < 4; et++) {
    oA[et] = (floatx4){0.f, 0.f, 0.f, 0.f};
    oB[et] = (floatx4){0.f, 0.f, 0.f, 0.f};
  }

  // prologue: tile 0 -> buf0; __syncthreads' intrinsic vmcnt(0) waits it (and Q loads)
  STAGE_KV(0, 0);
  __syncthreads();

  for (int kt = 0; kt <= tb; kt++) {
    int cur = kt & 1;
    if (kt < tb) STAGE_KV(kt + 1, cur ^ 1);   // buf^1 free since end-of-step kt-1
    const uint16_t* KB = &Ks[cur][0];
    const uint16_t* VB = &Vs[cur][0];
    bool doA = (kt <= ta);  // uniform across block

    // ---- S^T tiles + mask + exp2 + pack (P^T lands in B-layout of K=16 MFMA) ----
    s16x4 pbA[4], pbB[4];
    #pragma unroll
    for (int ct = 0; ct < 4; ct++) {
      int krow = (ct * 16 + l16) * 64;
      bf16x8 kb0 = *(const bf16x8*)&KB[krow + kc0];
      bf16x8 kb1 = *(const bf16x8*)&KB[krow + kc1];
      int key = kt * 64 + ct * 16 + quad * 4;
      floatx4 c = (floatx4){0.f, 0.f, 0.f, 0.f};
      c = __builtin_amdgcn_mfma_f32_16x16x32_bf16(kb0, aqB0, c, 0, 0, 0);
      c = __builtin_amdgcn_mfma_f32_16x16x32_bf16(kb1, aqB1, c, 0, 0, 0);
      #pragma unroll
      for (int r = 0; r < 4; r++) {
        float s = (kt == tb && key + r > rB) ? NEG_BIG : c[r];
        float p = __builtin_amdgcn_exp2f(s);
        lBs += p;
        pbB[ct][r] = (short)f2b(p);
      }
      if (doA) {
        floatx4 d = (floatx4){0.f, 0.f, 0.f, 0.f};
        d = __builtin_amdgcn_mfma_f32_16x16x32_bf16(kb0, aqA0, d, 0, 0, 0);
        d = __builtin_amdgcn_mfma_f32_16x16x32_bf16(kb1, aqA1, d, 0, 0, 0);
        #pragma unroll
        for (int r = 0; r < 4; r++) {
          float s = (kt == ta && key + r > rA) ? NEG_BIG : d[r];
          float p = __builtin_amdgcn_exp2f(s);
          lAs += p;
          pbA[ct][r] = (short)f2b(p);
        }
      }
    }
    // ---- O^T += V^T . P^T (A-frag = 4 keys of V^T via swizzled 8B reads) ----
    #pragma unroll
    for (int et = 0; et < 4; et++) {
      int vrow = (et * 16 + l16) * 64;
      #pragma unroll
      for (int ct = 0; ct < 4; ct++) {
        s16x4 va = *(const s16x4*)&VB[vrow + vcol[ct]];
        oB[et] = __builtin_amdgcn_mfma_f32_16x16x16bf16_1k(va, pbB[ct], oB[et], 0, 0, 0);
        if (doA)
          oA[et] = __builtin_amdgcn_mfma_f32_16x16x16bf16_1k(va, pbA[ct], oA[et], 0, 0, 0);
      }
    }
    __syncthreads();   // publishes buf^1 gll16s (intrinsic vmcnt(0)); retires buf reads
  }
#undef STAGE_KV

  // ---- reduce row-sums across the 4 quads, normalize, packed store ----
  lAs += __shfl_xor(lAs, 16, 64); lAs += __shfl_xor(lAs, 32, 64);
  lBs += __shfl_xor(lBs, 16, 64); lBs += __shfl_xor(lBs, 32, 64);
  float invA = 1.f / lAs, invB = 1.f / lBs;
  uint16_t* yb = Y + (size_t)b * NS * ND + (size_t)h * NHS;
  for (int et = 0; et < 4; et++) {
    __align__(8) uint16_t tA[4], tB[4];
    for (int r = 0; r < 4; r++) {
      tA[r] = f2b(oA[et][r] * invA);
      tB[r] = f2b(oB[et][r] * invB);
    }
    *(uint2*)&yb[(size_t)rA * ND + et * 16 + quad * 4] = *(uint2*)tA;
    *(uint2*)&yb[(size_t)rB * ND + et * 16 + quad * 4] = *(uint2*)tB;
  }
}
#else
// ---------------- fallback: round-8 k_attn (LDS-staged K/V + P round-trip) ----------------
__global__ __launch_bounds__(256) void k_attn(
    const uint16_t* __restrict__ Q, const uint16_t* __restrict__ K,
    const uint16_t* __restrict__ VT, uint16_t* __restrict__ Y) {
  __shared__ __align__(16) uint16_t Ks[64][72];
  __shared__ __align__(16) uint16_t Vs[64][72];
  __shared__ __align__(16) uint16_t Ps[4][2][16][72];
  int bh = blockIdx.y;
  int b = bh >> 4, h = bh & 15;
  int ta = blockIdx.x;
  int tb = 31 - ta;
  const uint16_t* Qp = Q + (size_t)bh * (NS * NHS);
  const uint16_t* Kp = K + (size_t)bh * (NS * NHS);
  const uint16_t* Vp = VT + (size_t)bh * (NS * NHS);
  int tid = threadIdx.x;
  int wv = tid >> 6, lane = tid & 63, quad = lane >> 4, l16 = lane & 15;

  int rA = ta * 64 + wv * 16 + l16;
  int rB = tb * 64 + wv * 16 + l16;
  bf16x8 aqA0 = *(const bf16x8*)&Qp[(size_t)rA * NHS + quad * 8];
  bf16x8 aqA1 = *(const bf16x8*)&Qp[(size_t)rA * NHS + 32 + quad * 8];
  bf16x8 aqB0 = *(const bf16x8*)&Qp[(size_t)rB * NHS + quad * 8];
  bf16x8 aqB1 = *(const bf16x8*)&Qp[(size_t)rB * NHS + 32 + quad * 8];

  float lA[4] = {0.f, 0.f, 0.f, 0.f}, lB[4] = {0.f, 0.f, 0.f, 0.f};
  floatx4 oA[4], oB[4];
  for (int ct = 0; ct < 4; ct++) {
    oA[ct] = (floatx4){0.f, 0.f, 0.f, 0.f};
    oB[ct] = (floatx4){0.f, 0.f, 0.f, 0.f};
  }
  for (int kt = 0; kt <= tb; kt++) {
    bool doA = (kt <= ta);
    __syncthreads();
    for (int u = tid; u < 512; u += 256) {
      int row = u >> 3, cg = u & 7;
      *(uint4*)&Ks[row][cg * 8] =
          *(const uint4*)&Kp[(size_t)(kt * 64 + row) * NHS + cg * 8];
    }
    for (int u = tid; u < 512; u += 256) {
      int row = u >> 3, cg = u & 7;
      *(uint4*)&Vs[row][cg * 8] =
          *(const uint4*)&Vp[(size_t)row * NS + kt * 64 + cg * 8];
    }
    __syncthreads();
    floatx4 sA[4], sB[4];
    for (int ct = 0; ct < 4; ct++) {
      bf16x8 kb0 = *(const bf16x8*)&Ks[ct * 16 + l16][quad * 8];
      bf16x8 kb1 = *(const bf16x8*)&Ks[ct * 16 + l16][32 + quad * 8];
      floatx4 c = (floatx4){0.f, 0.f, 0.f, 0.f};
      c = __builtin_amdgcn_mfma_f32_16x16x32_bf16(aqB0, kb0, c, 0, 0, 0);
      c = __builtin_amdgcn_mfma_f32_16x16x32_bf16(aqB1, kb1, c, 0, 0, 0);
      sB[ct] = c;
      if (doA) {
        floatx4 d = (floatx4){0.f, 0.f, 0.f, 0.f};
        d = __builtin_amdgcn_mfma_f32_16x16x32_bf16(aqA0, kb0, d, 0, 0, 0);
        d = __builtin_amdgcn_mfma_f32_16x16x32_bf16(aqA1, kb1, d, 0, 0, 0);
        sA[ct] = d;
      }
    }
    if (kt == tb) {
      int qrb = tb * 64 + wv * 16 + quad * 4;
      for (int ct = 0; ct < 4; ct++) {
        int kg = kt * 64 + ct * 16 + l16;
        for (int r = 0; r < 4; r++)
          sB[ct][r] = (kg <= qrb + r) ? sB[ct][r] : NEG_BIG;
      }
    }
    if (doA && kt == ta) {
      int qrb = ta * 64 + wv * 16 + quad * 4;
      for (int ct = 0; ct < 4; ct++) {
        int kg = kt * 64 + ct * 16 + l16;
        for (int r = 0; r < 4; r++)
          sA[ct][r] = (kg <= qrb + r) ? sA[ct][r] : NEG_BIG;
      }
    }
    for (int ct = 0; ct < 4; ct++)
      for (int r = 0; r < 4; r++) {
        float p = __builtin_amdgcn_exp2f(sB[ct][r]);
        lB[r] += p;
        Ps[wv][1][quad * 4 + r][ct * 16 + l16] = f2b(p);
      }
    if (doA)
      for (int ct = 0; ct < 4; ct++)
        for (int r = 0; r < 4; r++) {
          float p = __builtin_amdgcn_exp2f(sA[ct][r]);
          lA[r] += p;
          Ps[wv][0][quad * 4 + r][ct * 16 + l16] = f2b(p);
        }
    bf16x8 apB0 = *(const bf16x8*)&Ps[wv][1][l16][quad * 8];
    bf16x8 apB1 = *(const bf16x8*)&Ps[wv][1][l16][32 + quad * 8];
    bf16x8 apA0, apA1;
    if (doA) {
      apA0 = *(const bf16x8*)&Ps[wv][0][l16][quad * 8];
      apA1 = *(const bf16x8*)&Ps[wv][0][l16][32 + quad * 8];
    }
    for (int ct = 0; ct < 4; ct++) {
      bf16x8 vb0 = *(const bf16x8*)&Vs[ct * 16 + l16][quad * 8];
      bf16x8 vb1 = *(const bf16x8*)&Vs[ct * 16 + l16][32 + quad * 8];
      oB[ct] = __builtin_amdgcn_mfma_f32_16x16x32_bf16(apB0, vb0, oB[ct], 0, 0, 0);
      oB[ct] = __builtin_amdgcn_mfma_f32_16x16x32_bf16(apB1, vb1, oB[ct], 0, 0, 0);
      if (doA) {
        oA[ct] = __builtin_amdgcn_mfma_f32_16x16x32_bf16(apA0, vb0, oA[ct], 0, 0, 0);
        oA[ct] = __builtin_amdgcn_mfma_f32_16x16x32_bf16(apA1, vb1, oA[ct], 0, 0, 0);
      }
    }
  }
  for (int off = 1; off < 16; off <<= 1)
    for (int r = 0; r < 4; r++) {
      lA[r] += __shfl_xor(lA[r], off, 64);
      lB[r] += __shfl_xor(lB[r], off, 64);
    }
  uint16_t* yb = Y + (size_t)b * NS * ND + (size_t)h * NHS;
  for (int ct = 0; ct < 4; ct++)
    for (int r = 0; r < 4; r++) {
      int sA_ = ta * 64 + wv * 16 + quad * 4 + r;
      int sB_ = tb * 64 + wv * 16 + quad * 4 + r;
      yb[(size_t)sA_ * ND + ct * 16 + l16] = f2b(oA[ct][r] / lA[r]);
      yb[(size_t)sB_ * ND + ct * 16 + l16] = f2b(oB[ct][r] / lB[r]);
    }
}
#endif

// ---------------- kernel 3: output projection + bias, 128x128 2-phase (k_qkv recipe) ----
__global__ __launch_bounds__(512, 4) void k_proj(
    const uint16_t* __restrict__ y, const uint16_t* __restrict__ wot,
    const float* __restrict__ bo, float* __restrict__ out) {
  __shared__ __align__(16) uint16_t L[32768];   // 64 KB

  int bid = blockIdx.x;
  int xcd = bid & 7, idx = bid >> 3;     // 64 tiles per XCD chunk
  int mtile = xcd * 8 + (idx & 7);       // 8 m-tiles per XCD, inner
  int ntile = idx >> 3;                  // 8 n-tiles, outer
  int m0 = mtile * 128;
  int n0 = ntile * 128;

  int tid = threadIdx.x;
  int wave = tid >> 6, lane = tid & 63, quad = lane >> 4, l16 = lane & 15;
  int wr = wave >> 2, wc = wave & 3;

  int swc = ((tid & 3) ^ ((tid >> 4) & 3)) * 8;
  const uint16_t* pA = y + (size_t)(m0 + (tid >> 2)) * ND + swc;
  const uint16_t* pB = wot + (size_t)(n0 + (tid >> 2)) * ND + swc;
  const int stOff = wave * 512;

  const int rq = (quad ^ (l16 >> 2)) * 8;
  const int offA = (wr * 64 + l16) * 32 + rq;
  const int offB = (wc * 32 + l16) * 32 + rq;

  floatx4 acc[4][2];
  #pragma unroll
  for (int i = 0; i < 4; i++)
    #pragma unroll
    for (int j = 0; j < 2; j++) acc[i][j] = (floatx4){0.f, 0.f, 0.f, 0.f};

#define STAGE(A_)                                                               \
  do {                                                                          \
    int a_ = (A_);                                                              \
    if (a_ < 32) {                                                              \
      int ko_ = (a_ >> 1) * 64 + (a_ & 1) * 32;                                 \
      gll16(pA + ko_, &L[(a_ & 3) * 4096 + stOff]);                             \
      gll16(pB + ko_, &L[16384 + (a_ & 3) * 4096 + stOff]);                     \
    }                                                                           \
  } while (0)

#define PH_BAR()                         \
  do {                                   \
    asm volatile("" ::: "memory");       \
    __builtin_amdgcn_s_barrier();        \
    asm volatile("" ::: "memory");       \
  } while (0)

  STAGE(0); STAGE(1); STAGE(2);
  asm volatile("s_waitcnt vmcnt(4)" ::: "memory");
  PH_BAR();

#define MFMA8()                                                                           \
  _Pragma("unroll")                                                                       \
  for (int mt_ = 0; mt_ < 4; mt_++)                                                       \
    _Pragma("unroll")                                                                     \
    for (int nt_ = 0; nt_ < 2; nt_++)                                                     \
      acc[mt_][nt_] = __builtin_amdgcn_mfma_f32_16x16x32_bf16(af[mt_], bfr[nt_], acc[mt_][nt_], 0, 0, 0)

  for (int t = 0; t < 16; ++t) {
    {
      int sA = ((2 * t) & 3) * 4096;
      int sB = 16384 + ((2 * t) & 3) * 4096;
      bf16x8 af[4], bfr[2];
      #pragma unroll
      for (int i = 0; i < 4; i++) af[i] = *(const bf16x8*)&L[sA + offA + i * 512];
      #pragma unroll
      for (int i = 0; i < 2; i++) bfr[i] = *(const bf16x8*)&L[sB + offB + i * 512];
      STAGE(2 * t + 3);
      PH_BAR();
      __builtin_amdgcn_s_setprio(1);
      MFMA8();
      __builtin_amdgcn_s_setprio(0);
      if (t < 15) { asm volatile("s_waitcnt vmcnt(4)" ::: "memory"); }
      else        { asm volatile("s_waitcnt vmcnt(0)" ::: "memory"); }
      PH_BAR();
    }
    {
      int sA = ((2 * t + 1) & 3) * 4096;
      int sB = 16384 + ((2 * t + 1) & 3) * 4096;
      bf16x8 af[4], bfr[2];
      #pragma unroll
      for (int i = 0; i < 4; i++) af[i] = *(const bf16x8*)&L[sA + offA + i * 512];
      #pragma unroll
      for (int i = 0; i < 2; i++) bfr[i] = *(const bf16x8*)&L[sB + offB + i * 512];
      STAGE(2 * t + 4);
      PH_BAR();
      __builtin_amdgcn_s_setprio(1);
      MFMA8();
      __builtin_amdgcn_s_setprio(0);
      if (t < 14)       { asm volatile("s_waitcnt vmcnt(4)" ::: "memory"); }
      else if (t == 14) { asm volatile("s_waitcnt vmcnt(2)" ::: "memory"); }
      if (t < 15) PH_BAR();
    }
  }
#undef MFMA8
#undef STAGE
#undef PH_BAR

  // epilogue: fp32 out + bias (col n = n0 + wc*32 + nt*16 + l16)
  float bv[2];
  #pragma unroll
  for (int nt = 0; nt < 2; nt++) bv[nt] = bo[n0 + wc * 32 + nt * 16 + l16];
  #pragma unroll
  for (int mt = 0; mt < 4; mt++) {
    int s = m0 + wr * 64 + mt * 16 + quad * 4;
    #pragma unroll
    for (int nt = 0; nt < 2; nt++) {
      int n = n0 + wc * 32 + nt * 16 + l16;
      #pragma unroll
      for (int r = 0; r < 4; r++)
        out[(size_t)(s + r) * ND + n] = acc[mt][nt][r] + bv[nt];
    }
  }
}

extern "C" void kernel_launch(void* const* d_in, const int* in_sizes, int n_in,
                              void* d_out, int out_size, void* d_ws, size_t ws_size,
                              hipStream_t stream) {
  const float* x  = (const float*)d_in[0];
  const float* Wq = (const float*)d_in[1];
  const float* Wk = (const float*)d_in[2];
  const float* Wv = (const float*)d_in[3];
  const float* Wo = (const float*)d_in[4];
  const float* bo = (const float*)d_in[5];
  uint16_t* ws = (uint16_t*)d_ws;

  uint16_t* wt = ws;                       // 4 * WSLAB bf16 (Wq_t, Wk_t, Wv_t, Wo_t)
  uint16_t* xb = ws + 4 * WSLAB;           // XSLAB bf16
  uint16_t* q  = xb + XSLAB;               // QSLAB each; k contiguous after q
  uint16_t* k  = q + QSLAB;
  uint16_t* vt = k + QSLAB;                // QSLAB (V transposed, written by k_qkv)
  uint16_t* y  = vt + QSLAB;

  k_prep<<<dim3(5120), dim3(256), 0, stream>>>(x, Wq, Wk, Wv, Wo, xb, wt);
  k_qkv<<<dim3(768), dim3(512), 0, stream>>>(xb, wt, q, vt);
  k_attn<<<dim3(16, NB * NH), dim3(256), 0, stream>>>(q, k, vt, y);
  k_proj<<<dim3(512), dim3(512), 0, stream>>>(y, wt + 3 * WSLAB, bo, (float*)d_out);
}